// Round 5
// baseline (424.208 us; speedup 1.0000x reference)
//
#include <hip/hip_runtime.h>

// Problem constants (fixed by setup_inputs)
#define BATCH 4
#define DDIM 256
#define LLEN 4096
#define NTOK (BATCH * LLEN)   // 16384
#define KCODE 8192
#define COMMITMENT 0.25f
#define MARGIN 0.02f          // dot-units; ~9 sigma of bf16 sim-error diff
#define CAP 48                // candidate slots per token
#define SUBSET 4096           // codes scanned by S0 to build LB

typedef __attribute__((ext_vector_type(8))) short short8;
typedef __attribute__((ext_vector_type(8))) unsigned short ushort8;
typedef __attribute__((ext_vector_type(4))) float f32x4;

__device__ __forceinline__ unsigned short f2bf(float f) {
  unsigned u = __float_as_uint(f);
  unsigned r = (u + 0x7fffu + ((u >> 16) & 1u)) >> 16;
  return (unsigned short)r;
}

__device__ __forceinline__ void gld16(const void* g, void* l) {
  __builtin_amdgcn_global_load_lds(
      (const __attribute__((address_space(1))) unsigned int*)g,
      (__attribute__((address_space(3))) unsigned int*)l, 16, 0, 0);
}

// ---------------------------------------------------------------------------
// P1: transpose x [B,D,L] -> xT fp32 [N,D] and xt_frag bf16 (MFMA frag order).
// Also zero LB/count/loss accumulators. Block = 64 tokens.
// Frag order (row n, dim d): off = (n>>4)*4096 + (d>>5)*512
//                                  + (((d>>3)&3)*16 + (n&15))*8 + (d&7)
// ---------------------------------------------------------------------------
__global__ __launch_bounds__(256) void prep_x_kernel(
    const float* __restrict__ x, float* __restrict__ xT,
    unsigned short* __restrict__ xtf, unsigned int* __restrict__ LB,
    int* __restrict__ count, float* __restrict__ lossac) {
  __shared__ float As[256 * 65];
  const int tid = threadIdx.x;
  const int n0 = blockIdx.x * 64;
  const int b = n0 >> 12, l0 = n0 & 4095;
  const float* xb = x + ((size_t)b << 20) + l0;
  {
    const int t4 = (tid & 15) * 4, dof = tid >> 4;
#pragma unroll
    for (int p = 0; p < 16; ++p) {
      int d = p * 16 + dof;
      float4 v = *(const float4*)(xb + (size_t)d * LLEN + t4);
      As[d * 65 + t4 + 0] = v.x;
      As[d * 65 + t4 + 1] = v.y;
      As[d * 65 + t4 + 2] = v.z;
      As[d * 65 + t4 + 3] = v.w;
    }
  }
  __syncthreads();
  const int tok = tid >> 2, sub = tid & 3;
  const int n = n0 + tok;
#pragma unroll
  for (int q = 0; q < 16; ++q) {
    int d = q * 16 + sub * 4;
    float4 v = make_float4(As[(d + 0) * 65 + tok], As[(d + 1) * 65 + tok],
                           As[(d + 2) * 65 + tok], As[(d + 3) * 65 + tok]);
    *(float4*)(xT + (size_t)n * 256 + d) = v;
  }
#pragma unroll
  for (int q = 0; q < 8; ++q) {
    int d = (sub + q * 4) * 8;
    ushort8 u;
#pragma unroll
    for (int e = 0; e < 8; ++e) u[e] = f2bf(As[(d + e) * 65 + tok]);
    size_t off = ((size_t)(n >> 4)) * 4096 + q * 512 + (sub * 16 + (n & 15)) * 8;
    *(ushort8*)(xtf + off) = u;
  }
  if (tid < 64) {
    LB[n0 + tid] = 0u;
    count[n0 + tid] = 0;
  }
  if (blockIdx.x == 0 && tid == 0) *lossac = 0.0f;
}

// ---------------------------------------------------------------------------
// P2: codebook -> normalized bf16 frags (rnorm folded in) + rnorm fp32.
// Block = 64 codes, 4 threads per code.
// ---------------------------------------------------------------------------
__global__ __launch_bounds__(256) void prep_cb_kernel(
    const float* __restrict__ cb, unsigned short* __restrict__ cbf,
    float* __restrict__ rnorm) {
  const int tid = threadIdx.x;
  const int k = blockIdx.x * 64 + (tid >> 2), sub = tid & 3;
  const float* row = cb + (size_t)k * 256;
  float s = 0.0f;
#pragma unroll
  for (int q = 0; q < 8; ++q) {
    int d = (sub + q * 4) * 8;
    float4 v0 = *(const float4*)(row + d);
    float4 v1 = *(const float4*)(row + d + 4);
    s += v0.x * v0.x + v0.y * v0.y + v0.z * v0.z + v0.w * v0.w;
    s += v1.x * v1.x + v1.y * v1.y + v1.z * v1.z + v1.w * v1.w;
  }
  s += __shfl_xor(s, 1);
  s += __shfl_xor(s, 2);
  float rn = 1.0f / sqrtf(fmaxf(s, 1e-24f));
  if (sub == 0) rnorm[k] = rn;
#pragma unroll
  for (int q = 0; q < 8; ++q) {
    int d = (sub + q * 4) * 8;
    float4 v0 = *(const float4*)(row + d);
    float4 v1 = *(const float4*)(row + d + 4);
    ushort8 u;
    u[0] = f2bf(v0.x * rn); u[1] = f2bf(v0.y * rn);
    u[2] = f2bf(v0.z * rn); u[3] = f2bf(v0.w * rn);
    u[4] = f2bf(v1.x * rn); u[5] = f2bf(v1.y * rn);
    u[6] = f2bf(v1.z * rn); u[7] = f2bf(v1.w * rn);
    size_t off = ((size_t)(k >> 4)) * 4096 + q * 512 + (sub * 16 + (k & 15)) * 8;
    *(ushort8*)(cbf + off) = u;
  }
}

// ---------------------------------------------------------------------------
// simcore v3: A in LDS (read-only after one barrier), B streamed global->reg
// with a DISTANCE-2 prefetch ring (3 buffers, statically indexed under full
// unroll). No per-iteration barriers (v1's vmcnt(0)+s_barrier stall) and no
// register spill (v2's 57 MB/dispatch scratch traffic at VGPR cap 128).
// Budget: acc 64 + ring 48 + av 16 + misc ~25 ~= 155 VGPR.
// Block: 256 thr = 4 waves; per-wave 64 tokens (h half) x 64 codes (g half)
// per 128-code group; acc accumulates 8 chunks (256 dims), admit per group.
// S0 (MODE=0): max over SUBSET codes -> LB[token] (atomicMax).
// S1 (MODE=1): all codes; admit code if sim > LB - MARGIN.
// ---------------------------------------------------------------------------
template <int MODE>
__global__ __launch_bounds__(256, 2) void simcore_kernel(
    const unsigned short* __restrict__ xtf,
    const unsigned short* __restrict__ cbf, unsigned int* __restrict__ LB,
    int* __restrict__ count, int* __restrict__ cand) {
  __shared__ __align__(16) short Afrag[128 * 256];  // 64 KB
  const int tid = threadIdx.x;
  const int w = tid >> 6, lane = tid & 63;
  const int h = w & 1, g = w >> 1;
  const int n0 = blockIdx.x * 128;
  const int code0 = blockIdx.y * 1024;
  const int kg0 = (code0 >> 4) + g * 4;  // code 16-group base (incl. g half)

  // Stage A: 64 KB contiguous copy, 16 wave-rounds of 1 KB (linear dest).
  {
    const char* src = (const char*)(xtf + (size_t)n0 * 256);
#pragma unroll
    for (int i = 0; i < 16; ++i) {
      int off = (i * 4 + w) << 10;
      gld16(src + off + lane * 16, (char*)Afrag + off);
    }
  }

  f32x4 acc[4][4];
#pragma unroll
  for (int i = 0; i < 4; ++i)
#pragma unroll
    for (int j = 0; j < 4; ++j) acc[i][j] = (f32x4){0.f, 0.f, 0.f, 0.f};

  float rm[16];
  float lbm[16];
  if (MODE == 0) {
#pragma unroll
    for (int ir = 0; ir < 16; ++ir) rm[ir] = -1e30f;
  }
  if (MODE == 1) {
#pragma unroll
    for (int ir = 0; ir < 16; ++ir) {
      int token = n0 + h * 64 + (ir >> 2) * 16 + ((lane >> 4) << 2) + (ir & 3);
      lbm[ir] = __uint_as_float(LB[token]) - MARGIN;
    }
  }

  // B prefetch ring, distance 2. b[t%3] consumed at t; load t+2 into
  // b[(t+2)%3]. All indices compile-time (flat loop fully unrolled).
  short8 b[3][4];
#pragma unroll
  for (int t = 0; t < 2; ++t) {
    const unsigned short* p =
        cbf + ((size_t)(kg0 + (t >> 3) * 8)) * 4096 + (t & 7) * 512;
#pragma unroll
    for (int j = 0; j < 4; ++j)
      b[t][j] = *(const short8*)(p + (size_t)j * 4096 + lane * 8);
  }

  // One barrier total: wait A staging (global_load_lds -> vmcnt) then go.
  __syncthreads();

#pragma unroll
  for (int t = 0; t < 64; ++t) {
    const int c = t & 7;
    if (t + 2 < 64) {
      const int t2 = t + 2;
      const unsigned short* p =
          cbf + ((size_t)(kg0 + (t2 >> 3) * 8)) * 4096 + (t2 & 7) * 512;
#pragma unroll
      for (int j = 0; j < 4; ++j)
        b[t2 % 3][j] = *(const short8*)(p + (size_t)j * 4096 + lane * 8);
    }
    short8 av[4];
#pragma unroll
    for (int i = 0; i < 4; ++i)
      av[i] = *(const short8*)(Afrag + ((h * 4 + i) * 8 + c) * 512 + lane * 8);
    __builtin_amdgcn_s_setprio(1);
#pragma unroll
    for (int i = 0; i < 4; ++i)
#pragma unroll
      for (int j = 0; j < 4; ++j)
        acc[i][j] = __builtin_amdgcn_mfma_f32_16x16x32_bf16(
            av[i], b[t % 3][j], acc[i][j], 0, 0, 0);
    __builtin_amdgcn_s_setprio(0);

    if (c == 7) {
      const int cg = t >> 3;
      if (MODE == 0) {
#pragma unroll
        for (int i = 0; i < 4; ++i)
#pragma unroll
          for (int j = 0; j < 4; ++j)
#pragma unroll
            for (int r = 0; r < 4; ++r)
              rm[i * 4 + r] = fmaxf(rm[i * 4 + r], acc[i][j][r]);
      } else {
#pragma unroll
        for (int i = 0; i < 4; ++i)
#pragma unroll
          for (int j = 0; j < 4; ++j) {
            bool p0 = acc[i][j][0] > lbm[i * 4 + 0];
            bool p1 = acc[i][j][1] > lbm[i * 4 + 1];
            bool p2 = acc[i][j][2] > lbm[i * 4 + 2];
            bool p3 = acc[i][j][3] > lbm[i * 4 + 3];
            if (__any(p0 | p1 | p2 | p3)) {
#pragma unroll
              for (int r = 0; r < 4; ++r) {
                float v = acc[i][j][r];
                if (v > lbm[i * 4 + r]) {
                  int token = n0 + h * 64 + i * 16 + ((lane >> 4) << 2) + r;
                  int code = code0 + cg * 128 + g * 64 + j * 16 + (lane & 15);
                  int slot = atomicAdd(&count[token], 1);
                  if (slot < CAP) cand[(size_t)token * CAP + slot] = code;
                }
              }
            }
          }
      }
#pragma unroll
      for (int i = 0; i < 4; ++i)
#pragma unroll
        for (int j = 0; j < 4; ++j) acc[i][j] = (f32x4){0.f, 0.f, 0.f, 0.f};
    }
  }

  if (MODE == 0) {
#pragma unroll
    for (int ir = 0; ir < 16; ++ir) {
      float v = rm[ir];
      v = fmaxf(v, __shfl_xor(v, 1));
      v = fmaxf(v, __shfl_xor(v, 2));
      v = fmaxf(v, __shfl_xor(v, 4));
      v = fmaxf(v, __shfl_xor(v, 8));
      if ((lane & 15) == 0) {
        int tl = h * 64 + (ir >> 2) * 16 + ((lane >> 4) << 2) + (ir & 3);
        atomicMax(&LB[n0 + tl], __float_as_uint(v));
      }
    }
  }
}

// ---------------------------------------------------------------------------
// S3 v2: exact fp64 rescore, 4 candidates per wave in parallel (16 lanes
// each, 16 dims/lane). Division/sqrt-free comparator: p1/sqrt(c1) >
// p2/sqrt(c2)  <=>  sign split, then p1^2*c2 vs p2^2*c1 (flipped if both
// negative). Tie -> lower code index (matches jnp.argmax).
// ---------------------------------------------------------------------------
__device__ __forceinline__ bool better(double p1, double c1, int k1,
                                       double p2, double c2, int k2) {
  bool s1 = (p1 >= 0.0), s2 = (p2 >= 0.0);
  if (s1 != s2) return s1;
  double l = p1 * p1 * c2, r = p2 * p2 * c1;
  if (l != r) return s1 ? (l > r) : (l < r);
  return k1 < k2;
}

__global__ __launch_bounds__(256) void rescore_kernel(
    const float* __restrict__ xT, const float* __restrict__ cb,
    const int* __restrict__ count, const int* __restrict__ cand,
    int* __restrict__ besti_g) {
  const int w = threadIdx.x >> 6, lane = threadIdx.x & 63;
  const int t = blockIdx.x * 4 + w;
  const int q = lane >> 4, r = lane & 15;
  double xd[16];
  {
    const float* xr = xT + (size_t)t * 256 + r * 16;
#pragma unroll
    for (int u = 0; u < 4; ++u) {
      float4 v = *(const float4*)(xr + u * 4);
      xd[u * 4 + 0] = v.x; xd[u * 4 + 1] = v.y;
      xd[u * 4 + 2] = v.z; xd[u * 4 + 3] = v.w;
    }
  }
  const int cnt = min(count[t], CAP);
  double bp = -1.0e300, bcc = 1.0;
  int bi = 0;  // cnt >= 1 guaranteed (best code always admitted)
  for (int s = 0; s < cnt; s += 4) {
    const int sq = s + q;
    int k = (sq < cnt) ? cand[(size_t)t * CAP + sq] : 0;
    const float* row = cb + (size_t)k * 256 + r * 16;
    double p = 0.0, cc = 0.0;
#pragma unroll
    for (int u = 0; u < 4; ++u) {
      float4 v = *(const float4*)(row + u * 4);
      p += xd[u * 4 + 0] * (double)v.x + xd[u * 4 + 1] * (double)v.y +
           xd[u * 4 + 2] * (double)v.z + xd[u * 4 + 3] * (double)v.w;
      cc += (double)v.x * v.x + (double)v.y * v.y + (double)v.z * v.z +
            (double)v.w * v.w;
    }
#pragma unroll
    for (int m = 1; m < 16; m <<= 1) {
      p += __shfl_xor(p, m);
      cc += __shfl_xor(cc, m);
    }
    if (sq >= cnt) p = -1.0e300;  // masked slot loses to any real candidate
    // Tournament across the 4 quarter-wave candidates.
    {
      double op = __shfl_xor(p, 16), occ = __shfl_xor(cc, 16);
      int ok = __shfl_xor(k, 16);
      if (better(op, occ, ok, p, cc, k)) { p = op; cc = occ; k = ok; }
    }
    {
      double op = __shfl_xor(p, 32), occ = __shfl_xor(cc, 32);
      int ok = __shfl_xor(k, 32);
      if (better(op, occ, ok, p, cc, k)) { p = op; cc = occ; k = ok; }
    }
    if (better(p, cc, k, bp, bcc, bi)) { bp = p; bcc = cc; bi = k; }
  }
  if (lane == 0) besti_g[t] = bi;
}

// ---------------------------------------------------------------------------
// Epilogue v2: LDS-staged transpose-gather. Block = 64 tokens (fixed b, l0).
// ---------------------------------------------------------------------------
__global__ __launch_bounds__(256) void epilogue_kernel(
    const float* __restrict__ x, const float* __restrict__ cb,
    const float* __restrict__ rnorm, const int* __restrict__ besti_g,
    float* __restrict__ out, float* __restrict__ loss_accum) {
  __shared__ float QT[256 * 68];  // QT[d][t], pad 68 (2-way bank alias: free)
  __shared__ int idxs[64];
  __shared__ float lred[4];
  const int tid = threadIdx.x;
  const int n0 = blockIdx.x * 64;
  const int b = n0 >> 12, l0 = n0 & 4095;

  if (tid < 64) idxs[tid] = besti_g[n0 + tid];
  __syncthreads();

  {
    const int t = tid >> 2, sub = tid & 3;
    const int idx = idxs[t];
    const float rn = rnorm[idx];
    const float* row = cb + (size_t)idx * 256;
#pragma unroll
    for (int p = 0; p < 16; ++p) {
      const int d = p * 16 + sub * 4;
      float4 v = *(const float4*)(row + d);
      QT[(d + 0) * 68 + t] = v.x * rn;
      QT[(d + 1) * 68 + t] = v.y * rn;
      QT[(d + 2) * 68 + t] = v.z * rn;
      QT[(d + 3) * 68 + t] = v.w * rn;
    }
  }
  __syncthreads();

  float part = 0.0f;
  {
    const int t4 = (tid & 15) * 4;
    const int d0 = tid >> 4;  // 0..15
#pragma unroll
    for (int p = 0; p < 16; ++p) {
      const int d = p * 16 + d0;
      const size_t o = ((size_t)(b * 256 + d) << 12) + l0 + t4;
      float4 qv = *(const float4*)(&QT[d * 68 + t4]);
      float4 xv = *(const float4*)(x + o);
      *(float4*)(out + o) = qv;
      float e0 = qv.x - xv.x, e1 = qv.y - xv.y, e2 = qv.z - xv.z,
            e3 = qv.w - xv.w;
      part += e0 * e0 + e1 * e1 + e2 * e2 + e3 * e3;
    }
  }
#pragma unroll
  for (int off = 32; off > 0; off >>= 1) part += __shfl_down(part, off);
  const int w = tid >> 6, lane = tid & 63;
  if (lane == 0) lred[w] = part;
  __syncthreads();
  if (tid == 0)
    atomicAdd(loss_accum, lred[0] + lred[1] + lred[2] + lred[3]);
}

__global__ void finalize_kernel(const float* __restrict__ loss_accum,
                                float* __restrict__ out_loss) {
  *out_loss = COMMITMENT * (*loss_accum) / (float)((size_t)NTOK * DDIM);
}

extern "C" void kernel_launch(void* const* d_in, const int* in_sizes, int n_in,
                              void* d_out, int out_size, void* d_ws,
                              size_t ws_size, hipStream_t stream) {
  const float* x = (const float*)d_in[0];   // [4,256,4096]
  const float* cb = (const float*)d_in[1];  // [8192,256]
  float* out = (float*)d_out;

  char* ws = (char*)d_ws;
  unsigned short* xtf = (unsigned short*)(ws);              // 8 MB
  unsigned short* cbf = (unsigned short*)(ws + 8388608);    // 4 MB
  float* xT = (float*)(ws + 12582912);                      // 16 MB
  int* cand = (int*)(ws + 29360128);                        // 3 MB (16384*48*4)
  float* rnorm = (float*)(ws + 32505856);                   // 32 KB
  unsigned int* LB = (unsigned int*)(ws + 32538624);        // 64 KB
  int* count = (int*)(ws + 32604160);                       // 64 KB
  int* besti = (int*)(ws + 32669696);                       // 64 KB
  float* lossac = (float*)(ws + 32735232);                  // 4 B

  prep_x_kernel<<<NTOK / 64, 256, 0, stream>>>(x, xT, xtf, LB, count, lossac);
  prep_cb_kernel<<<KCODE / 64, 256, 0, stream>>>(cb, cbf, rnorm);
  simcore_kernel<0><<<dim3(NTOK / 128, SUBSET / 1024), 256, 0, stream>>>(
      xtf, cbf, LB, count, cand);
  simcore_kernel<1><<<dim3(NTOK / 128, KCODE / 1024), 256, 0, stream>>>(
      xtf, cbf, LB, count, cand);
  rescore_kernel<<<NTOK / 4, 256, 0, stream>>>(xT, cb, count, cand, besti);
  epilogue_kernel<<<NTOK / 64, 256, 0, stream>>>(x, cb, rnorm, besti, out,
                                                 lossac);
  finalize_kernel<<<1, 1, 0, stream>>>(lossac, out + (out_size - 1));
}

// Round 6
// 196.897 us; speedup vs baseline: 2.1545x; 2.1545x over previous
//
#include <hip/hip_runtime.h>

// Problem constants (fixed by setup_inputs)
#define BATCH 4
#define DDIM 256
#define LLEN 4096
#define NTOK (BATCH * LLEN)   // 16384
#define KCODE 8192
#define COMMITMENT 0.25f
#define MARGIN 0.02f          // dot-units; ~9 sigma of bf16 sim-error diff
#define CAP 48                // candidate slots per token
#define SUBSET 4096           // codes scanned by S0 to build LB

typedef __attribute__((ext_vector_type(8))) short short8;
typedef __attribute__((ext_vector_type(8))) unsigned short ushort8;
typedef __attribute__((ext_vector_type(4))) float f32x4;

__device__ __forceinline__ unsigned short f2bf(float f) {
  unsigned u = __float_as_uint(f);
  unsigned r = (u + 0x7fffu + ((u >> 16) & 1u)) >> 16;
  return (unsigned short)r;
}

__device__ __forceinline__ void gld16(const void* g, void* l) {
  __builtin_amdgcn_global_load_lds(
      (const __attribute__((address_space(1))) unsigned int*)g,
      (__attribute__((address_space(3))) unsigned int*)l, 16, 0, 0);
}

// ---------------------------------------------------------------------------
// P1: transpose x [B,D,L] -> xT fp32 [N,D] and xt_frag bf16 (MFMA frag order).
// Also zero LB/count/loss accumulators. Block = 64 tokens.
// Frag order (row n, dim d): off = (n>>4)*4096 + (d>>5)*512
//                                  + (((d>>3)&3)*16 + (n&15))*8 + (d&7)
// ---------------------------------------------------------------------------
__global__ __launch_bounds__(256) void prep_x_kernel(
    const float* __restrict__ x, float* __restrict__ xT,
    unsigned short* __restrict__ xtf, unsigned int* __restrict__ LB,
    int* __restrict__ count, float* __restrict__ lossac) {
  __shared__ float As[256 * 65];
  const int tid = threadIdx.x;
  const int n0 = blockIdx.x * 64;
  const int b = n0 >> 12, l0 = n0 & 4095;
  const float* xb = x + ((size_t)b << 20) + l0;
  {
    const int t4 = (tid & 15) * 4, dof = tid >> 4;
#pragma unroll
    for (int p = 0; p < 16; ++p) {
      int d = p * 16 + dof;
      float4 v = *(const float4*)(xb + (size_t)d * LLEN + t4);
      As[d * 65 + t4 + 0] = v.x;
      As[d * 65 + t4 + 1] = v.y;
      As[d * 65 + t4 + 2] = v.z;
      As[d * 65 + t4 + 3] = v.w;
    }
  }
  __syncthreads();
  const int tok = tid >> 2, sub = tid & 3;
  const int n = n0 + tok;
#pragma unroll
  for (int q = 0; q < 16; ++q) {
    int d = q * 16 + sub * 4;
    float4 v = make_float4(As[(d + 0) * 65 + tok], As[(d + 1) * 65 + tok],
                           As[(d + 2) * 65 + tok], As[(d + 3) * 65 + tok]);
    *(float4*)(xT + (size_t)n * 256 + d) = v;
  }
#pragma unroll
  for (int q = 0; q < 8; ++q) {
    int d = (sub + q * 4) * 8;
    ushort8 u;
#pragma unroll
    for (int e = 0; e < 8; ++e) u[e] = f2bf(As[(d + e) * 65 + tok]);
    size_t off = ((size_t)(n >> 4)) * 4096 + q * 512 + (sub * 16 + (n & 15)) * 8;
    *(ushort8*)(xtf + off) = u;
  }
  if (tid < 64) {
    LB[n0 + tid] = 0u;
    count[n0 + tid] = 0;
  }
  if (blockIdx.x == 0 && tid == 0) *lossac = 0.0f;
}

// ---------------------------------------------------------------------------
// P2: codebook -> normalized bf16 frags (rnorm folded in) + rnorm fp32.
// Block = 64 codes, 4 threads per code.
// ---------------------------------------------------------------------------
__global__ __launch_bounds__(256) void prep_cb_kernel(
    const float* __restrict__ cb, unsigned short* __restrict__ cbf,
    float* __restrict__ rnorm) {
  const int tid = threadIdx.x;
  const int k = blockIdx.x * 64 + (tid >> 2), sub = tid & 3;
  const float* row = cb + (size_t)k * 256;
  float s = 0.0f;
#pragma unroll
  for (int q = 0; q < 8; ++q) {
    int d = (sub + q * 4) * 8;
    float4 v0 = *(const float4*)(row + d);
    float4 v1 = *(const float4*)(row + d + 4);
    s += v0.x * v0.x + v0.y * v0.y + v0.z * v0.z + v0.w * v0.w;
    s += v1.x * v1.x + v1.y * v1.y + v1.z * v1.z + v1.w * v1.w;
  }
  s += __shfl_xor(s, 1);
  s += __shfl_xor(s, 2);
  float rn = 1.0f / sqrtf(fmaxf(s, 1e-24f));
  if (sub == 0) rnorm[k] = rn;
#pragma unroll
  for (int q = 0; q < 8; ++q) {
    int d = (sub + q * 4) * 8;
    float4 v0 = *(const float4*)(row + d);
    float4 v1 = *(const float4*)(row + d + 4);
    ushort8 u;
    u[0] = f2bf(v0.x * rn); u[1] = f2bf(v0.y * rn);
    u[2] = f2bf(v0.z * rn); u[3] = f2bf(v0.w * rn);
    u[4] = f2bf(v1.x * rn); u[5] = f2bf(v1.y * rn);
    u[6] = f2bf(v1.z * rn); u[7] = f2bf(v1.w * rn);
    size_t off = ((size_t)(k >> 4)) * 4096 + q * 512 + (sub * 16 + (k & 15)) * 8;
    *(ushort8*)(cbf + off) = u;
  }
}

// ---------------------------------------------------------------------------
// simcore v4: A in LDS (one barrier), B streamed global->reg through FOUR
// NAMED buffers b0..b3 (no array indexing -> no local-memory demotion, the
// v3 failure: 900 MB scratch from b[t%3] under a refused unroll). Pipeline:
// issue loads for chunks c+2,c+3 into one named pair, run 32 MFMAs (~310
// wave-cyc, covers L2 latency) on the other pair, alternate. cg loop stays
// rolled; every buffer/acc reference is compile-time static.
// Budget: b0..b3 64 + acc 64 + av 16 + lbm/rm 16 + misc ~30 ~= 190 VGPR.
// Block: 256 thr = 4 waves; per-wave 64 tokens (h) x 64 codes (g) per
// 128-code group; acc accumulates 8 chunks (256 dims), epilogue per group.
// S0 (MODE=0): max over SUBSET codes -> LB[token] (atomicMax).
// S1 (MODE=1): all codes; admit code if sim > LB - MARGIN.
// ---------------------------------------------------------------------------
template <int MODE>
__global__ __launch_bounds__(256, 2) void simcore_kernel(
    const unsigned short* __restrict__ xtf,
    const unsigned short* __restrict__ cbf, unsigned int* __restrict__ LB,
    int* __restrict__ count, int* __restrict__ cand) {
  __shared__ __align__(16) short Afrag[128 * 256];  // 64 KB
  const int tid = threadIdx.x;
  const int w = tid >> 6, lane = tid & 63;
  const int h = w & 1, g = w >> 1;
  const int n0 = blockIdx.x * 128;
  const int code0 = blockIdx.y * 1024;
  const int kg0 = (code0 >> 4) + g * 4;  // code 16-group base (incl. g half)

  // Stage A: 64 KB contiguous copy, 16 wave-rounds of 1 KB (linear dest).
  {
    const char* src = (const char*)(xtf + (size_t)n0 * 256);
#pragma unroll
    for (int i = 0; i < 16; ++i) {
      int off = (i * 4 + w) << 10;
      gld16(src + off + lane * 16, (char*)Afrag + off);
    }
  }

  f32x4 acc[4][4];
#pragma unroll
  for (int i = 0; i < 4; ++i)
#pragma unroll
    for (int j = 0; j < 4; ++j) acc[i][j] = (f32x4){0.f, 0.f, 0.f, 0.f};

  float rm[16];
  float lbm[16];
  if (MODE == 0) {
#pragma unroll
    for (int ir = 0; ir < 16; ++ir) rm[ir] = -1e30f;
  }
  if (MODE == 1) {
#pragma unroll
    for (int ir = 0; ir < 16; ++ir) {
      int token = n0 + h * 64 + (ir >> 2) * 16 + ((lane >> 4) << 2) + (ir & 3);
      lbm[ir] = __uint_as_float(LB[token]) - MARGIN;
    }
  }

  // Wave's B base: chunk (cg, c, j) lives at bw + (cg*8 + j)*4096 + c*512.
  const unsigned short* bw = cbf + (size_t)kg0 * 4096 + lane * 8;

#define LOADB(buf, cgi, ci)                                                   \
  {                                                                           \
    const unsigned short* _p = bw + (size_t)(cgi) * 8 * 4096 + (ci) * 512;    \
    _Pragma("unroll") for (int j = 0; j < 4; ++j)                             \
        buf[j] = *(const short8*)(_p + (size_t)j * 4096);                     \
  }

#define STEP(buf, ci)                                                         \
  {                                                                           \
    short8 av[4];                                                             \
    _Pragma("unroll") for (int i = 0; i < 4; ++i)                             \
        av[i] = *(const short8*)(Afrag + ((h * 4 + i) * 8 + (ci)) * 512 +     \
                                 lane * 8);                                   \
    __builtin_amdgcn_s_setprio(1);                                            \
    _Pragma("unroll") for (int i = 0; i < 4; ++i)                             \
        _Pragma("unroll") for (int j = 0; j < 4; ++j)                         \
            acc[i][j] = __builtin_amdgcn_mfma_f32_16x16x32_bf16(              \
                av[i], buf[j], acc[i][j], 0, 0, 0);                           \
    __builtin_amdgcn_s_setprio(0);                                            \
  }

  short8 b0[4], b1[4], b2[4], b3[4];
  LOADB(b0, 0, 0);
  LOADB(b1, 0, 1);

  // One barrier total: wait A staging (global_load_lds) then free-run.
  __syncthreads();

  for (int cg = 0; cg < 8; ++cg) {
    LOADB(b2, cg, 2);
    LOADB(b3, cg, 3);
    STEP(b0, 0);
    STEP(b1, 1);
    LOADB(b0, cg, 4);
    LOADB(b1, cg, 5);
    STEP(b2, 2);
    STEP(b3, 3);
    LOADB(b2, cg, 6);
    LOADB(b3, cg, 7);
    STEP(b0, 4);
    STEP(b1, 5);
    {
      const int cgn = (cg < 7) ? cg + 1 : 7;  // clamped re-read, L2-hot
      LOADB(b0, cgn, 0);
      LOADB(b1, cgn, 1);
    }
    STEP(b2, 6);
    STEP(b3, 7);

    // Group epilogue: 128 codes finished for this wave's 64-code slice.
    if (MODE == 0) {
#pragma unroll
      for (int i = 0; i < 4; ++i)
#pragma unroll
        for (int j = 0; j < 4; ++j)
#pragma unroll
          for (int r = 0; r < 4; ++r)
            rm[i * 4 + r] = fmaxf(rm[i * 4 + r], acc[i][j][r]);
    } else {
#pragma unroll
      for (int i = 0; i < 4; ++i)
#pragma unroll
        for (int j = 0; j < 4; ++j) {
          bool p0 = acc[i][j][0] > lbm[i * 4 + 0];
          bool p1 = acc[i][j][1] > lbm[i * 4 + 1];
          bool p2 = acc[i][j][2] > lbm[i * 4 + 2];
          bool p3 = acc[i][j][3] > lbm[i * 4 + 3];
          if (__any(p0 | p1 | p2 | p3)) {
#pragma unroll
            for (int r = 0; r < 4; ++r) {
              float v = acc[i][j][r];
              if (v > lbm[i * 4 + r]) {
                int token = n0 + h * 64 + i * 16 + ((lane >> 4) << 2) + r;
                int code = code0 + cg * 128 + g * 64 + j * 16 + (lane & 15);
                int slot = atomicAdd(&count[token], 1);
                if (slot < CAP) cand[(size_t)token * CAP + slot] = code;
              }
            }
          }
        }
    }
#pragma unroll
    for (int i = 0; i < 4; ++i)
#pragma unroll
      for (int j = 0; j < 4; ++j) acc[i][j] = (f32x4){0.f, 0.f, 0.f, 0.f};
  }

#undef LOADB
#undef STEP

  if (MODE == 0) {
#pragma unroll
    for (int ir = 0; ir < 16; ++ir) {
      float v = rm[ir];
      v = fmaxf(v, __shfl_xor(v, 1));
      v = fmaxf(v, __shfl_xor(v, 2));
      v = fmaxf(v, __shfl_xor(v, 4));
      v = fmaxf(v, __shfl_xor(v, 8));
      if ((lane & 15) == 0) {
        int tl = h * 64 + (ir >> 2) * 16 + ((lane >> 4) << 2) + (ir & 3);
        atomicMax(&LB[n0 + tl], __float_as_uint(v));
      }
    }
  }
}

// ---------------------------------------------------------------------------
// S3 v2: exact fp64 rescore, 4 candidates per wave in parallel (16 lanes
// each, 16 dims/lane). Division/sqrt-free comparator: p1/sqrt(c1) >
// p2/sqrt(c2)  <=>  sign split, then p1^2*c2 vs p2^2*c1 (flipped if both
// negative). Tie -> lower code index (matches jnp.argmax).
// ---------------------------------------------------------------------------
__device__ __forceinline__ bool better(double p1, double c1, int k1,
                                       double p2, double c2, int k2) {
  bool s1 = (p1 >= 0.0), s2 = (p2 >= 0.0);
  if (s1 != s2) return s1;
  double l = p1 * p1 * c2, r = p2 * p2 * c1;
  if (l != r) return s1 ? (l > r) : (l < r);
  return k1 < k2;
}

__global__ __launch_bounds__(256) void rescore_kernel(
    const float* __restrict__ xT, const float* __restrict__ cb,
    const int* __restrict__ count, const int* __restrict__ cand,
    int* __restrict__ besti_g) {
  const int w = threadIdx.x >> 6, lane = threadIdx.x & 63;
  const int t = blockIdx.x * 4 + w;
  const int q = lane >> 4, r = lane & 15;
  double xd[16];
  {
    const float* xr = xT + (size_t)t * 256 + r * 16;
#pragma unroll
    for (int u = 0; u < 4; ++u) {
      float4 v = *(const float4*)(xr + u * 4);
      xd[u * 4 + 0] = v.x; xd[u * 4 + 1] = v.y;
      xd[u * 4 + 2] = v.z; xd[u * 4 + 3] = v.w;
    }
  }
  const int cnt = min(count[t], CAP);
  double bp = -1.0e300, bcc = 1.0;
  int bi = 0;  // cnt >= 1 guaranteed (best code always admitted)
  for (int s = 0; s < cnt; s += 4) {
    const int sq = s + q;
    int k = (sq < cnt) ? cand[(size_t)t * CAP + sq] : 0;
    const float* row = cb + (size_t)k * 256 + r * 16;
    double p = 0.0, cc = 0.0;
#pragma unroll
    for (int u = 0; u < 4; ++u) {
      float4 v = *(const float4*)(row + u * 4);
      p += xd[u * 4 + 0] * (double)v.x + xd[u * 4 + 1] * (double)v.y +
           xd[u * 4 + 2] * (double)v.z + xd[u * 4 + 3] * (double)v.w;
      cc += (double)v.x * v.x + (double)v.y * v.y + (double)v.z * v.z +
            (double)v.w * v.w;
    }
#pragma unroll
    for (int m = 1; m < 16; m <<= 1) {
      p += __shfl_xor(p, m);
      cc += __shfl_xor(cc, m);
    }
    if (sq >= cnt) p = -1.0e300;  // masked slot loses to any real candidate
    // Tournament across the 4 quarter-wave candidates.
    {
      double op = __shfl_xor(p, 16), occ = __shfl_xor(cc, 16);
      int ok = __shfl_xor(k, 16);
      if (better(op, occ, ok, p, cc, k)) { p = op; cc = occ; k = ok; }
    }
    {
      double op = __shfl_xor(p, 32), occ = __shfl_xor(cc, 32);
      int ok = __shfl_xor(k, 32);
      if (better(op, occ, ok, p, cc, k)) { p = op; cc = occ; k = ok; }
    }
    if (better(p, cc, k, bp, bcc, bi)) { bp = p; bcc = cc; bi = k; }
  }
  if (lane == 0) besti_g[t] = bi;
}

// ---------------------------------------------------------------------------
// Epilogue v2: LDS-staged transpose-gather. Block = 64 tokens (fixed b, l0).
// ---------------------------------------------------------------------------
__global__ __launch_bounds__(256) void epilogue_kernel(
    const float* __restrict__ x, const float* __restrict__ cb,
    const float* __restrict__ rnorm, const int* __restrict__ besti_g,
    float* __restrict__ out, float* __restrict__ loss_accum) {
  __shared__ float QT[256 * 68];  // QT[d][t], pad 68 (2-way bank alias: free)
  __shared__ int idxs[64];
  __shared__ float lred[4];
  const int tid = threadIdx.x;
  const int n0 = blockIdx.x * 64;
  const int b = n0 >> 12, l0 = n0 & 4095;

  if (tid < 64) idxs[tid] = besti_g[n0 + tid];
  __syncthreads();

  {
    const int t = tid >> 2, sub = tid & 3;
    const int idx = idxs[t];
    const float rn = rnorm[idx];
    const float* row = cb + (size_t)idx * 256;
#pragma unroll
    for (int p = 0; p < 16; ++p) {
      const int d = p * 16 + sub * 4;
      float4 v = *(const float4*)(row + d);
      QT[(d + 0) * 68 + t] = v.x * rn;
      QT[(d + 1) * 68 + t] = v.y * rn;
      QT[(d + 2) * 68 + t] = v.z * rn;
      QT[(d + 3) * 68 + t] = v.w * rn;
    }
  }
  __syncthreads();

  float part = 0.0f;
  {
    const int t4 = (tid & 15) * 4;
    const int d0 = tid >> 4;  // 0..15
#pragma unroll
    for (int p = 0; p < 16; ++p) {
      const int d = p * 16 + d0;
      const size_t o = ((size_t)(b * 256 + d) << 12) + l0 + t4;
      float4 qv = *(const float4*)(&QT[d * 68 + t4]);
      float4 xv = *(const float4*)(x + o);
      *(float4*)(out + o) = qv;
      float e0 = qv.x - xv.x, e1 = qv.y - xv.y, e2 = qv.z - xv.z,
            e3 = qv.w - xv.w;
      part += e0 * e0 + e1 * e1 + e2 * e2 + e3 * e3;
    }
  }
#pragma unroll
  for (int off = 32; off > 0; off >>= 1) part += __shfl_down(part, off);
  const int w = tid >> 6, lane = tid & 63;
  if (lane == 0) lred[w] = part;
  __syncthreads();
  if (tid == 0)
    atomicAdd(loss_accum, lred[0] + lred[1] + lred[2] + lred[3]);
}

__global__ void finalize_kernel(const float* __restrict__ loss_accum,
                                float* __restrict__ out_loss) {
  *out_loss = COMMITMENT * (*loss_accum) / (float)((size_t)NTOK * DDIM);
}

extern "C" void kernel_launch(void* const* d_in, const int* in_sizes, int n_in,
                              void* d_out, int out_size, void* d_ws,
                              size_t ws_size, hipStream_t stream) {
  const float* x = (const float*)d_in[0];   // [4,256,4096]
  const float* cb = (const float*)d_in[1];  // [8192,256]
  float* out = (float*)d_out;

  char* ws = (char*)d_ws;
  unsigned short* xtf = (unsigned short*)(ws);              // 8 MB
  unsigned short* cbf = (unsigned short*)(ws + 8388608);    // 4 MB
  float* xT = (float*)(ws + 12582912);                      // 16 MB
  int* cand = (int*)(ws + 29360128);                        // 3 MB (16384*48*4)
  float* rnorm = (float*)(ws + 32505856);                   // 32 KB
  unsigned int* LB = (unsigned int*)(ws + 32538624);        // 64 KB
  int* count = (int*)(ws + 32604160);                       // 64 KB
  int* besti = (int*)(ws + 32669696);                       // 64 KB
  float* lossac = (float*)(ws + 32735232);                  // 4 B

  prep_x_kernel<<<NTOK / 64, 256, 0, stream>>>(x, xT, xtf, LB, count, lossac);
  prep_cb_kernel<<<KCODE / 64, 256, 0, stream>>>(cb, cbf, rnorm);
  simcore_kernel<0><<<dim3(NTOK / 128, SUBSET / 1024), 256, 0, stream>>>(
      xtf, cbf, LB, count, cand);
  simcore_kernel<1><<<dim3(NTOK / 128, KCODE / 1024), 256, 0, stream>>>(
      xtf, cbf, LB, count, cand);
  rescore_kernel<<<NTOK / 4, 256, 0, stream>>>(xT, cb, count, cand, besti);
  epilogue_kernel<<<NTOK / 64, 256, 0, stream>>>(x, cb, rnorm, besti, out,
                                                 lossac);
  finalize_kernel<<<1, 1, 0, stream>>>(lossac, out + (out_size - 1));
}

// Round 9
// 194.478 us; speedup vs baseline: 2.1813x; 1.0124x over previous
//
#include <hip/hip_runtime.h>

// Problem constants (fixed by setup_inputs)
#define BATCH 4
#define DDIM 256
#define LLEN 4096
#define NTOK (BATCH * LLEN)   // 16384
#define KCODE 8192
#define COMMITMENT 0.25f
#define MARGIN 0.02f          // dot-units; ~9 sigma of bf16 sim-error diff
#define CAP 48                // candidate slots per token
#define SUBSET 4096           // codes scanned by S0 to build LB.
                              // DO NOT SHRINK: SUBSET=1024 overflows CAP on
                              // tail tokens (worst LB ~2.35sigma -> ~174
                              // admits > 48) and drops the true argmax
                              // (r7/r8 identical absmax 0.2856).

typedef __attribute__((ext_vector_type(8))) short short8;
typedef __attribute__((ext_vector_type(8))) unsigned short ushort8;
typedef __attribute__((ext_vector_type(4))) float f32x4;

__device__ __forceinline__ unsigned short f2bf(float f) {
  unsigned u = __float_as_uint(f);
  unsigned r = (u + 0x7fffu + ((u >> 16) & 1u)) >> 16;
  return (unsigned short)r;
}

__device__ __forceinline__ void gld16(const void* g, void* l) {
  __builtin_amdgcn_global_load_lds(
      (const __attribute__((address_space(1))) unsigned int*)g,
      (__attribute__((address_space(3))) unsigned int*)l, 16, 0, 0);
}

// ---------------------------------------------------------------------------
// P1: transpose x [B,D,L] -> xT fp32 [N,D] and xt_frag bf16 (MFMA frag order).
// Also zero LB/count/loss accumulators. Block = 64 tokens.
// Frag order (row n, dim d): off = (n>>4)*4096 + (d>>5)*512
//                                  + (((d>>3)&3)*16 + (n&15))*8 + (d&7)
// ---------------------------------------------------------------------------
__global__ __launch_bounds__(256) void prep_x_kernel(
    const float* __restrict__ x, float* __restrict__ xT,
    unsigned short* __restrict__ xtf, unsigned int* __restrict__ LB,
    int* __restrict__ count, float* __restrict__ lossac) {
  __shared__ float As[256 * 65];
  const int tid = threadIdx.x;
  const int n0 = blockIdx.x * 64;
  const int b = n0 >> 12, l0 = n0 & 4095;
  const float* xb = x + ((size_t)b << 20) + l0;
  {
    const int t4 = (tid & 15) * 4, dof = tid >> 4;
#pragma unroll
    for (int p = 0; p < 16; ++p) {
      int d = p * 16 + dof;
      float4 v = *(const float4*)(xb + (size_t)d * LLEN + t4);
      As[d * 65 + t4 + 0] = v.x;
      As[d * 65 + t4 + 1] = v.y;
      As[d * 65 + t4 + 2] = v.z;
      As[d * 65 + t4 + 3] = v.w;
    }
  }
  __syncthreads();
  const int tok = tid >> 2, sub = tid & 3;
  const int n = n0 + tok;
#pragma unroll
  for (int q = 0; q < 16; ++q) {
    int d = q * 16 + sub * 4;
    float4 v = make_float4(As[(d + 0) * 65 + tok], As[(d + 1) * 65 + tok],
                           As[(d + 2) * 65 + tok], As[(d + 3) * 65 + tok]);
    *(float4*)(xT + (size_t)n * 256 + d) = v;
  }
#pragma unroll
  for (int q = 0; q < 8; ++q) {
    int d = (sub + q * 4) * 8;
    ushort8 u;
#pragma unroll
    for (int e = 0; e < 8; ++e) u[e] = f2bf(As[(d + e) * 65 + tok]);
    size_t off = ((size_t)(n >> 4)) * 4096 + q * 512 + (sub * 16 + (n & 15)) * 8;
    *(ushort8*)(xtf + off) = u;
  }
  if (tid < 64) {
    LB[n0 + tid] = 0u;
    count[n0 + tid] = 0;
  }
  if (blockIdx.x == 0 && tid == 0) *lossac = 0.0f;
}

// ---------------------------------------------------------------------------
// P2: codebook -> normalized bf16 frags (rnorm folded in) + rnorm fp32.
// CHUNK-MAJOR layout: element offset for code k, dim-chunk q (dims q*32..+31):
//   (k>>6)*16384 + q*2048 + ((k>>4)&3)*512 + (sub*16 + (k&15))*8
// One LOADB's four 16-code rows sit 512 elem (1 KB) apart -> imm-offset
// foldable in simcore (cuts per-load address VALU). Verified bijective onto
// [0, 2M) elements. Block = 64 codes, 4 threads per code.
// ---------------------------------------------------------------------------
__global__ __launch_bounds__(256) void prep_cb_kernel(
    const float* __restrict__ cb, unsigned short* __restrict__ cbf,
    float* __restrict__ rnorm) {
  const int tid = threadIdx.x;
  const int k = blockIdx.x * 64 + (tid >> 2), sub = tid & 3;
  const float* row = cb + (size_t)k * 256;
  float s = 0.0f;
#pragma unroll
  for (int q = 0; q < 8; ++q) {
    int d = (sub + q * 4) * 8;
    float4 v0 = *(const float4*)(row + d);
    float4 v1 = *(const float4*)(row + d + 4);
    s += v0.x * v0.x + v0.y * v0.y + v0.z * v0.z + v0.w * v0.w;
    s += v1.x * v1.x + v1.y * v1.y + v1.z * v1.z + v1.w * v1.w;
  }
  s += __shfl_xor(s, 1);
  s += __shfl_xor(s, 2);
  float rn = 1.0f / sqrtf(fmaxf(s, 1e-24f));
  if (sub == 0) rnorm[k] = rn;
#pragma unroll
  for (int q = 0; q < 8; ++q) {
    int d = (sub + q * 4) * 8;
    float4 v0 = *(const float4*)(row + d);
    float4 v1 = *(const float4*)(row + d + 4);
    ushort8 u;
    u[0] = f2bf(v0.x * rn); u[1] = f2bf(v0.y * rn);
    u[2] = f2bf(v0.z * rn); u[3] = f2bf(v0.w * rn);
    u[4] = f2bf(v1.x * rn); u[5] = f2bf(v1.y * rn);
    u[6] = f2bf(v1.z * rn); u[7] = f2bf(v1.w * rn);
    size_t off = ((size_t)(k >> 6)) * 16384 + q * 2048 +
                 (size_t)((k >> 4) & 3) * 512 + (sub * 16 + (k & 15)) * 8;
    *(ushort8*)(cbf + off) = u;
  }
}

// ---------------------------------------------------------------------------
// simcore v6: A in LDS (one barrier), B streamed global->reg through FOUR
// NAMED buffers b0..b3 with DISTANCE-3 rotation: each LOADB has 3 STEPs
// (~240 wave-cyc of MFMA) between issue and consume, covering ~200 cyc L2
// latency. All buffer names static (v3's b[t%3] scratch demotion stays
// fixed). Chunk-major cbf: LOADB's 4 loads are base+{0,512,1024,1536} elem
// -> imm-offset folded. Rotation invariant: entering cg, b0=(cg,0),
// b1=(cg,1), b2=(cg,2).
// S0 (MODE=0): max over SUBSET codes -> LB[token] (atomicMax).
// S1 (MODE=1): all codes; admit code if sim > LB - MARGIN.
// ---------------------------------------------------------------------------
template <int MODE>
__global__ __launch_bounds__(256, 2) void simcore_kernel(
    const unsigned short* __restrict__ xtf,
    const unsigned short* __restrict__ cbf, unsigned int* __restrict__ LB,
    int* __restrict__ count, int* __restrict__ cand) {
  __shared__ __align__(16) short Afrag[128 * 256];  // 64 KB
  const int tid = threadIdx.x;
  const int w = tid >> 6, lane = tid & 63;
  const int h = w & 1, g = w >> 1;
  const int n0 = blockIdx.x * 128;
  const int code0 = blockIdx.y * 1024;

  // Stage A: 64 KB contiguous copy, 16 wave-rounds of 1 KB (linear dest).
  {
    const char* src = (const char*)(xtf + (size_t)n0 * 256);
#pragma unroll
    for (int i = 0; i < 16; ++i) {
      int off = (i * 4 + w) << 10;
      gld16(src + off + lane * 16, (char*)Afrag + off);
    }
  }

  f32x4 acc[4][4];
#pragma unroll
  for (int i = 0; i < 4; ++i)
#pragma unroll
    for (int j = 0; j < 4; ++j) acc[i][j] = (f32x4){0.f, 0.f, 0.f, 0.f};

  float rm[16];
  float lbm[16];
  if (MODE == 0) {
#pragma unroll
    for (int ir = 0; ir < 16; ++ir) rm[ir] = -1e30f;
  }
  if (MODE == 1) {
#pragma unroll
    for (int ir = 0; ir < 16; ++ir) {
      int token = n0 + h * 64 + (ir >> 2) * 16 + ((lane >> 4) << 2) + (ir & 3);
      lbm[ir] = __uint_as_float(LB[token]) - MARGIN;
    }
  }

  // Wave's B base in chunk-major layout: 64-code super-group index =
  // code0/64 + cg*2 + g. Chunk (cg,c) at bw + cg*32768 + c*2048, j rows at
  // +j*512 (imm-foldable).
  const unsigned short* bw =
      cbf + ((size_t)(code0 >> 6) + g) * 16384 + lane * 8;

#define LOADB(buf, cgi, ci)                                                   \
  {                                                                           \
    const unsigned short* _p = bw + (size_t)(cgi) * 32768 + (ci) * 2048;      \
    _Pragma("unroll") for (int j = 0; j < 4; ++j)                             \
        buf[j] = *(const short8*)(_p + j * 512);                              \
  }

#define STEP(buf, ci)                                                         \
  {                                                                           \
    short8 av[4];                                                             \
    _Pragma("unroll") for (int i = 0; i < 4; ++i)                             \
        av[i] = *(const short8*)(Afrag + ((h * 4 + i) * 8 + (ci)) * 512 +     \
                                 lane * 8);                                   \
    __builtin_amdgcn_s_setprio(1);                                            \
    _Pragma("unroll") for (int i = 0; i < 4; ++i)                             \
        _Pragma("unroll") for (int j = 0; j < 4; ++j)                         \
            acc[i][j] = __builtin_amdgcn_mfma_f32_16x16x32_bf16(              \
                av[i], buf[j], acc[i][j], 0, 0, 0);                           \
    __builtin_amdgcn_s_setprio(0);                                            \
  }

  short8 b0[4], b1[4], b2[4], b3[4];
  LOADB(b0, 0, 0);
  LOADB(b1, 0, 1);
  LOADB(b2, 0, 2);

  // One barrier total: wait A staging (global_load_lds) then free-run.
  __syncthreads();

  for (int cg = 0; cg < 8; ++cg) {
    const int cgn = (cg < 7) ? cg + 1 : 7;  // clamped prefetch, L2-hot
    LOADB(b3, cg, 3);
    STEP(b0, 0);
    LOADB(b0, cg, 4);
    STEP(b1, 1);
    LOADB(b1, cg, 5);
    STEP(b2, 2);
    LOADB(b2, cg, 6);
    STEP(b3, 3);
    LOADB(b3, cg, 7);
    STEP(b0, 4);
    LOADB(b0, cgn, 0);
    STEP(b1, 5);
    LOADB(b1, cgn, 1);
    STEP(b2, 6);
    LOADB(b2, cgn, 2);
    STEP(b3, 7);

    // Group epilogue: 128 codes finished for this wave's 64-code slice.
    if (MODE == 0) {
#pragma unroll
      for (int i = 0; i < 4; ++i)
#pragma unroll
        for (int j = 0; j < 4; ++j)
#pragma unroll
          for (int r = 0; r < 4; ++r)
            rm[i * 4 + r] = fmaxf(rm[i * 4 + r], acc[i][j][r]);
    } else {
#pragma unroll
      for (int i = 0; i < 4; ++i)
#pragma unroll
        for (int j = 0; j < 4; ++j) {
          bool p0 = acc[i][j][0] > lbm[i * 4 + 0];
          bool p1 = acc[i][j][1] > lbm[i * 4 + 1];
          bool p2 = acc[i][j][2] > lbm[i * 4 + 2];
          bool p3 = acc[i][j][3] > lbm[i * 4 + 3];
          if (__any(p0 | p1 | p2 | p3)) {
#pragma unroll
            for (int r = 0; r < 4; ++r) {
              float v = acc[i][j][r];
              if (v > lbm[i * 4 + r]) {
                int token = n0 + h * 64 + i * 16 + ((lane >> 4) << 2) + r;
                int code = code0 + cg * 128 + g * 64 + j * 16 + (lane & 15);
                int slot = atomicAdd(&count[token], 1);
                if (slot < CAP) cand[(size_t)token * CAP + slot] = code;
              }
            }
          }
        }
    }
#pragma unroll
    for (int i = 0; i < 4; ++i)
#pragma unroll
      for (int j = 0; j < 4; ++j) acc[i][j] = (f32x4){0.f, 0.f, 0.f, 0.f};
  }

#undef LOADB
#undef STEP

  if (MODE == 0) {
#pragma unroll
    for (int ir = 0; ir < 16; ++ir) {
      float v = rm[ir];
      v = fmaxf(v, __shfl_xor(v, 1));
      v = fmaxf(v, __shfl_xor(v, 2));
      v = fmaxf(v, __shfl_xor(v, 4));
      v = fmaxf(v, __shfl_xor(v, 8));
      if ((lane & 15) == 0) {
        int tl = h * 64 + (ir >> 2) * 16 + ((lane >> 4) << 2) + (ir & 3);
        atomicMax(&LB[n0 + tl], __float_as_uint(v));
      }
    }
  }
}

// ---------------------------------------------------------------------------
// S3 v2: exact fp64 rescore, 4 candidates per wave in parallel (16 lanes
// each, 16 dims/lane). Division/sqrt-free comparator: p1/sqrt(c1) >
// p2/sqrt(c2)  <=>  sign split, then p1^2*c2 vs p2^2*c1 (flipped if both
// negative). Tie -> lower code index (matches jnp.argmax).
// ---------------------------------------------------------------------------
__device__ __forceinline__ bool better(double p1, double c1, int k1,
                                       double p2, double c2, int k2) {
  bool s1 = (p1 >= 0.0), s2 = (p2 >= 0.0);
  if (s1 != s2) return s1;
  double l = p1 * p1 * c2, r = p2 * p2 * c1;
  if (l != r) return s1 ? (l > r) : (l < r);
  return k1 < k2;
}

__global__ __launch_bounds__(256) void rescore_kernel(
    const float* __restrict__ xT, const float* __restrict__ cb,
    const int* __restrict__ count, const int* __restrict__ cand,
    int* __restrict__ besti_g) {
  const int w = threadIdx.x >> 6, lane = threadIdx.x & 63;
  const int t = blockIdx.x * 4 + w;
  const int q = lane >> 4, r = lane & 15;
  double xd[16];
  {
    const float* xr = xT + (size_t)t * 256 + r * 16;
#pragma unroll
    for (int u = 0; u < 4; ++u) {
      float4 v = *(const float4*)(xr + u * 4);
      xd[u * 4 + 0] = v.x; xd[u * 4 + 1] = v.y;
      xd[u * 4 + 2] = v.z; xd[u * 4 + 3] = v.w;
    }
  }
  const int cnt = min(count[t], CAP);
  double bp = -1.0e300, bcc = 1.0;
  int bi = 0;  // cnt >= 1 guaranteed (best code always admitted)
  for (int s = 0; s < cnt; s += 4) {
    const int sq = s + q;
    int k = (sq < cnt) ? cand[(size_t)t * CAP + sq] : 0;
    const float* row = cb + (size_t)k * 256 + r * 16;
    double p = 0.0, cc = 0.0;
#pragma unroll
    for (int u = 0; u < 4; ++u) {
      float4 v = *(const float4*)(row + u * 4);
      p += xd[u * 4 + 0] * (double)v.x + xd[u * 4 + 1] * (double)v.y +
           xd[u * 4 + 2] * (double)v.z + xd[u * 4 + 3] * (double)v.w;
      cc += (double)v.x * v.x + (double)v.y * v.y + (double)v.z * v.z +
            (double)v.w * v.w;
    }
#pragma unroll
    for (int m = 1; m < 16; m <<= 1) {
      p += __shfl_xor(p, m);
      cc += __shfl_xor(cc, m);
    }
    if (sq >= cnt) p = -1.0e300;  // masked slot loses to any real candidate
    // Tournament across the 4 quarter-wave candidates.
    {
      double op = __shfl_xor(p, 16), occ = __shfl_xor(cc, 16);
      int ok = __shfl_xor(k, 16);
      if (better(op, occ, ok, p, cc, k)) { p = op; cc = occ; k = ok; }
    }
    {
      double op = __shfl_xor(p, 32), occ = __shfl_xor(cc, 32);
      int ok = __shfl_xor(k, 32);
      if (better(op, occ, ok, p, cc, k)) { p = op; cc = occ; k = ok; }
    }
    if (better(p, cc, k, bp, bcc, bi)) { bp = p; bcc = cc; bi = k; }
  }
  if (lane == 0) besti_g[t] = bi;
}

// ---------------------------------------------------------------------------
// Epilogue v2: LDS-staged transpose-gather. Block = 64 tokens (fixed b, l0).
// ---------------------------------------------------------------------------
__global__ __launch_bounds__(256) void epilogue_kernel(
    const float* __restrict__ x, const float* __restrict__ cb,
    const float* __restrict__ rnorm, const int* __restrict__ besti_g,
    float* __restrict__ out, float* __restrict__ loss_accum) {
  __shared__ float QT[256 * 68];  // QT[d][t], pad 68 (2-way bank alias: free)
  __shared__ int idxs[64];
  __shared__ float lred[4];
  const int tid = threadIdx.x;
  const int n0 = blockIdx.x * 64;
  const int b = n0 >> 12, l0 = n0 & 4095;

  if (tid < 64) idxs[tid] = besti_g[n0 + tid];
  __syncthreads();

  {
    const int t = tid >> 2, sub = tid & 3;
    const int idx = idxs[t];
    const float rn = rnorm[idx];
    const float* row = cb + (size_t)idx * 256;
#pragma unroll
    for (int p = 0; p < 16; ++p) {
      const int d = p * 16 + sub * 4;
      float4 v = *(const float4*)(row + d);
      QT[(d + 0) * 68 + t] = v.x * rn;
      QT[(d + 1) * 68 + t] = v.y * rn;
      QT[(d + 2) * 68 + t] = v.z * rn;
      QT[(d + 3) * 68 + t] = v.w * rn;
    }
  }
  __syncthreads();

  float part = 0.0f;
  {
    const int t4 = (tid & 15) * 4;
    const int d0 = tid >> 4;  // 0..15
#pragma unroll
    for (int p = 0; p < 16; ++p) {
      const int d = p * 16 + d0;
      const size_t o = ((size_t)(b * 256 + d) << 12) + l0 + t4;
      float4 qv = *(const float4*)(&QT[d * 68 + t4]);
      float4 xv = *(const float4*)(x + o);
      *(float4*)(out + o) = qv;
      float e0 = qv.x - xv.x, e1 = qv.y - xv.y, e2 = qv.z - xv.z,
            e3 = qv.w - xv.w;
      part += e0 * e0 + e1 * e1 + e2 * e2 + e3 * e3;
    }
  }
#pragma unroll
  for (int off = 32; off > 0; off >>= 1) part += __shfl_down(part, off);
  const int w = tid >> 6, lane = tid & 63;
  if (lane == 0) lred[w] = part;
  __syncthreads();
  if (tid == 0)
    atomicAdd(loss_accum, lred[0] + lred[1] + lred[2] + lred[3]);
}

__global__ void finalize_kernel(const float* __restrict__ loss_accum,
                                float* __restrict__ out_loss) {
  *out_loss = COMMITMENT * (*loss_accum) / (float)((size_t)NTOK * DDIM);
}

extern "C" void kernel_launch(void* const* d_in, const int* in_sizes, int n_in,
                              void* d_out, int out_size, void* d_ws,
                              size_t ws_size, hipStream_t stream) {
  const float* x = (const float*)d_in[0];   // [4,256,4096]
  const float* cb = (const float*)d_in[1];  // [8192,256]
  float* out = (float*)d_out;

  char* ws = (char*)d_ws;
  unsigned short* xtf = (unsigned short*)(ws);              // 8 MB
  unsigned short* cbf = (unsigned short*)(ws + 8388608);    // 4 MB
  float* xT = (float*)(ws + 12582912);                      // 16 MB
  int* cand = (int*)(ws + 29360128);                        // 3 MB (16384*48*4)
  float* rnorm = (float*)(ws + 32505856);                   // 32 KB
  unsigned int* LB = (unsigned int*)(ws + 32538624);        // 64 KB
  int* count = (int*)(ws + 32604160);                       // 64 KB
  int* besti = (int*)(ws + 32669696);                       // 64 KB
  float* lossac = (float*)(ws + 32735232);                  // 4 B

  prep_x_kernel<<<NTOK / 64, 256, 0, stream>>>(x, xT, xtf, LB, count, lossac);
  prep_cb_kernel<<<KCODE / 64, 256, 0, stream>>>(cb, cbf, rnorm);
  simcore_kernel<0><<<dim3(NTOK / 128, SUBSET / 1024), 256, 0, stream>>>(
      xtf, cbf, LB, count, cand);
  simcore_kernel<1><<<dim3(NTOK / 128, KCODE / 1024), 256, 0, stream>>>(
      xtf, cbf, LB, count, cand);
  rescore_kernel<<<NTOK / 4, 256, 0, stream>>>(xT, cb, count, cand, besti);
  epilogue_kernel<<<NTOK / 64, 256, 0, stream>>>(x, cb, rnorm, besti, out,
                                                 lossac);
  finalize_kernel<<<1, 1, 0, stream>>>(lossac, out + (out_size - 1));
}